// Round 1
// baseline (207.490 us; speedup 1.0000x reference)
//
#include <hip/hip_runtime.h>

#define NNODES 20000
#define DIM    512
#define BATCH  2048
#define NDRUG  2000
#define H1     128
#define H2     64
#define KHALF  32
#define NITEM  65      // 1 pos + 64 neg per sample
#define ROWS   16      // rows per block in layer1

// ---------------------------------------------------------------------------
// Kernel 1: build layer-1 tables.
//   P[j]  = embed[j]   @ W1[0:512]    (j < 2000; used by heads: h, n_h)
//   Q[j]  = embed[j]   @ W1[512:1024] (j < 2000; used by tails: n_t)
//   Qt[b] = embed[t[b]]@ W1[512:1024] (b < 2048; tail for pos and neg2)
// Blocks [0,125): P+Q for 16 nodes each. Blocks [125,253): Qt for 16 b each.
// ---------------------------------------------------------------------------
__global__ __launch_bounds__(128) void layer1_kernel(
    const float* __restrict__ embed, const float* __restrict__ W1,
    const int* __restrict__ t, float* __restrict__ P, float* __restrict__ Q,
    float* __restrict__ Qt, int nPQblocks)
{
    __shared__ float lds_e[ROWS * DIM];   // 32 KB
    const int blk = blockIdx.x;
    const int tid = threadIdx.x;          // 0..127, one output o per thread
    const bool isPQ = blk < nPQblocks;
    const int rowbase = isPQ ? blk * ROWS : (blk - nPQblocks) * ROWS;

    // Stage 16 embed rows (coalesced float4 loads: 2048 float4 / 128 threads)
    #pragma unroll
    for (int i = 0; i < 16; ++i) {
        int idx = i * 128 + tid;          // [0, 2048)
        int r   = idx >> 7;               // row 0..15
        int c4  = idx & 127;              // float4 within row
        int grow = isPQ ? (rowbase + r) : t[rowbase + r];
        float4 v = *(const float4*)(embed + (size_t)grow * DIM + c4 * 4);
        *(float4*)(lds_e + r * DIM + c4 * 4) = v;
    }
    __syncthreads();

    const int o = tid;
    float accT[ROWS], accB[ROWS];
    #pragma unroll
    for (int r = 0; r < ROWS; ++r) { accT[r] = 0.f; accB[r] = 0.f; }

    if (isPQ) {
        for (int d = 0; d < DIM; d += 4) {
            float wt0 = W1[(d + 0) * H1 + o];
            float wt1 = W1[(d + 1) * H1 + o];
            float wt2 = W1[(d + 2) * H1 + o];
            float wt3 = W1[(d + 3) * H1 + o];
            float wb0 = W1[(DIM + d + 0) * H1 + o];
            float wb1 = W1[(DIM + d + 1) * H1 + o];
            float wb2 = W1[(DIM + d + 2) * H1 + o];
            float wb3 = W1[(DIM + d + 3) * H1 + o];
            #pragma unroll
            for (int r = 0; r < ROWS; ++r) {
                float4 e = *(const float4*)(lds_e + r * DIM + d);  // broadcast
                accT[r] = fmaf(e.x, wt0, accT[r]);
                accT[r] = fmaf(e.y, wt1, accT[r]);
                accT[r] = fmaf(e.z, wt2, accT[r]);
                accT[r] = fmaf(e.w, wt3, accT[r]);
                accB[r] = fmaf(e.x, wb0, accB[r]);
                accB[r] = fmaf(e.y, wb1, accB[r]);
                accB[r] = fmaf(e.z, wb2, accB[r]);
                accB[r] = fmaf(e.w, wb3, accB[r]);
            }
        }
        #pragma unroll
        for (int r = 0; r < ROWS; ++r) {
            P[(size_t)(rowbase + r) * H1 + o] = accT[r];
            Q[(size_t)(rowbase + r) * H1 + o] = accB[r];
        }
    } else {
        for (int d = 0; d < DIM; d += 4) {
            float wb0 = W1[(DIM + d + 0) * H1 + o];
            float wb1 = W1[(DIM + d + 1) * H1 + o];
            float wb2 = W1[(DIM + d + 2) * H1 + o];
            float wb3 = W1[(DIM + d + 3) * H1 + o];
            #pragma unroll
            for (int r = 0; r < ROWS; ++r) {
                float4 e = *(const float4*)(lds_e + r * DIM + d);
                accB[r] = fmaf(e.x, wb0, accB[r]);
                accB[r] = fmaf(e.y, wb1, accB[r]);
                accB[r] = fmaf(e.z, wb2, accB[r]);
                accB[r] = fmaf(e.w, wb3, accB[r]);
            }
        }
        #pragma unroll
        for (int r = 0; r < ROWS; ++r)
            Qt[(size_t)(rowbase + r) * H1 + o] = accB[r];
    }
}

// ---------------------------------------------------------------------------
// Kernel 2: score all 133,120 rows. One lane per row.
//   row = b*65 + item. item 0 -> pos; 1..32 -> neg1 (P[h[b]] + Q[n_s[b][k]]);
//   33..64 -> neg2 (P[n_s[b][32+k]] + Qt[b]).
// W2/b1/b2/W3 accessed at wave-uniform addresses -> scalar loads; the lane's
// own work is pure FMA: 128x64 layer-2 + 64 layer-3.
// ---------------------------------------------------------------------------
__global__ __launch_bounds__(256) void score_kernel(
    const float* __restrict__ P, const float* __restrict__ Q,
    const float* __restrict__ Qt,
    const float* __restrict__ b1, const float* __restrict__ W2,
    const float* __restrict__ b2, const float* __restrict__ W3,
    const float* __restrict__ b3,
    const int* __restrict__ h, const int* __restrict__ ns,
    float* __restrict__ out)
{
    const int gid  = blockIdx.x * blockDim.x + threadIdx.x;  // 0..133119
    const int b    = gid / NITEM;
    const int item = gid - b * NITEM;

    const float* Pr;
    const float* Qr;
    if (item == 0) {
        Pr = P  + (size_t)h[b] * H1;
        Qr = Qt + (size_t)b * H1;
    } else if (item <= KHALF) {
        Pr = P + (size_t)h[b] * H1;
        Qr = Q + (size_t)ns[b * 64 + (item - 1)] * H1;
    } else {
        Pr = P  + (size_t)ns[b * 64 + 32 + (item - 33)] * H1;
        Qr = Qt + (size_t)b * H1;
    }

    float acc[H2];
    #pragma unroll
    for (int j = 0; j < H2; ++j) acc[j] = 0.f;

    for (int o = 0; o < H1; o += 4) {
        float4 p4 = *(const float4*)(Pr + o);
        float4 q4 = *(const float4*)(Qr + o);
        float h0 = fmaxf(p4.x + q4.x + b1[o + 0], 0.f);
        float h1v = fmaxf(p4.y + q4.y + b1[o + 1], 0.f);
        float h2v = fmaxf(p4.z + q4.z + b1[o + 2], 0.f);
        float h3v = fmaxf(p4.w + q4.w + b1[o + 3], 0.f);
        #pragma unroll
        for (int j = 0; j < H2; ++j) {
            float a = acc[j];
            a = fmaf(h0,  W2[(o + 0) * H2 + j], a);
            a = fmaf(h1v, W2[(o + 1) * H2 + j], a);
            a = fmaf(h2v, W2[(o + 2) * H2 + j], a);
            a = fmaf(h3v, W2[(o + 3) * H2 + j], a);
            acc[j] = a;
        }
    }

    float outv = b3[0];
    #pragma unroll
    for (int j = 0; j < H2; ++j) {
        float hh = fmaxf(acc[j] + b2[j], 0.f);
        outv = fmaf(hh, W3[j], outv);
    }

    if (item == 0) out[b] = outv;
    else           out[BATCH + (size_t)b * 64 + (item - 1)] = outv;
}

extern "C" void kernel_launch(void* const* d_in, const int* in_sizes, int n_in,
                              void* d_out, int out_size, void* d_ws, size_t ws_size,
                              hipStream_t stream) {
    const float* embed = (const float*)d_in[0];
    const float* W1    = (const float*)d_in[1];
    const float* b1    = (const float*)d_in[2];
    const float* W2    = (const float*)d_in[3];
    const float* b2    = (const float*)d_in[4];
    const float* W3    = (const float*)d_in[5];
    const float* b3    = (const float*)d_in[6];
    const int*   h     = (const int*)d_in[7];
    const int*   t     = (const int*)d_in[8];
    const int*   ns    = (const int*)d_in[9];
    float* out = (float*)d_out;

    float* P  = (float*)d_ws;            // 2000*128 f32
    float* Q  = P + NDRUG * H1;          // 2000*128 f32
    float* Qt = Q + NDRUG * H1;          // 2048*128 f32  (total ~3.0 MB)

    const int nPQ = NDRUG / ROWS;        // 125
    const int nQt = BATCH / ROWS;        // 128
    layer1_kernel<<<nPQ + nQt, 128, 0, stream>>>(embed, W1, t, P, Q, Qt, nPQ);

    const int nrows = BATCH * NITEM;     // 133120, divisible by 256
    score_kernel<<<nrows / 256, 256, 0, stream>>>(P, Q, Qt, b1, W2, b2, W3, b3,
                                                  h, ns, out);
}

// Round 2
// 183.679 us; speedup vs baseline: 1.1296x; 1.1296x over previous
//
#include <hip/hip_runtime.h>

#define NNODES 20000
#define DIM    512
#define BATCH  2048
#define NDRUG  2000
#define H1     128
#define H2     64
#define KHALF  32
#define NITEM  65        // 1 pos + 64 neg per sample
#define DHALF  256       // d-columns per split in layer1
#define SLAB   774144    // floats per partial slab: (2000+2000+2048)*128

// ---------------------------------------------------------------------------
// Kernel 1: layer-1 partial GEMMs, D split in 2 halves for 2x parallelism.
//   slab s covers d in [s*256, s*256+256)
//   P[j]  += embed[j][d]    @ W1[d,      :]   (j < 2000)
//   Q[j]  += embed[j][d]    @ W1[512+d,  :]   (j < 2000)
//   Qt[b] += embed[t[b]][d] @ W1[512+d,  :]   (b < 2048)
// grid (253, 2): x<125 -> P+Q (16 nodes), x>=125 -> Qt (16 batch rows).
// block 256 = 2 row-groups (8 rows each) x 128 outputs.
// ---------------------------------------------------------------------------
__global__ __launch_bounds__(256) void layer1_partial(
    const float* __restrict__ embed, const float* __restrict__ W1,
    const int* __restrict__ t, float* __restrict__ ws)
{
    __shared__ float lds_e[16 * DHALF];   // 16 KB
    const int s   = blockIdx.y;           // d-split 0/1
    const int blk = blockIdx.x;           // 0..252
    const bool isPQ = blk < 125;
    const int rowbase = isPQ ? blk * 16 : (blk - 125) * 16;
    const int o  = threadIdx.x & 127;     // output column
    const int rg = threadIdx.x >> 7;      // row-group 0/1
    const int d0 = s * DHALF;

    // Stage 16 rows x 256 d-cols (1024 float4 / 256 threads = 4 each)
    #pragma unroll
    for (int i = 0; i < 4; ++i) {
        int idx = i * 256 + threadIdx.x;  // float4 slot 0..1023
        int r   = idx >> 6;               // 64 float4 per row
        int c4  = idx & 63;
        int grow = isPQ ? (rowbase + r) : t[rowbase + r];
        float4 v = *(const float4*)(embed + (size_t)grow * DIM + d0 + c4 * 4);
        *(float4*)(lds_e + r * DHALF + c4 * 4) = v;
    }
    __syncthreads();

    float* Pp  = ws + (size_t)s * SLAB;           // partial slab base
    float* Qp  = Pp + NDRUG * H1;
    float* Qtp = Qp + NDRUG * H1;

    if (isPQ) {
        float accT[8], accB[8];
        #pragma unroll
        for (int r = 0; r < 8; ++r) { accT[r] = 0.f; accB[r] = 0.f; }
        for (int d = 0; d < DHALF; d += 4) {
            float wt0 = W1[(d0 + d + 0) * H1 + o];
            float wt1 = W1[(d0 + d + 1) * H1 + o];
            float wt2 = W1[(d0 + d + 2) * H1 + o];
            float wt3 = W1[(d0 + d + 3) * H1 + o];
            float wb0 = W1[(DIM + d0 + d + 0) * H1 + o];
            float wb1 = W1[(DIM + d0 + d + 1) * H1 + o];
            float wb2 = W1[(DIM + d0 + d + 2) * H1 + o];
            float wb3 = W1[(DIM + d0 + d + 3) * H1 + o];
            #pragma unroll
            for (int r = 0; r < 8; ++r) {
                float4 e = *(const float4*)(lds_e + (rg * 8 + r) * DHALF + d);
                accT[r] = fmaf(e.x, wt0, accT[r]);
                accT[r] = fmaf(e.y, wt1, accT[r]);
                accT[r] = fmaf(e.z, wt2, accT[r]);
                accT[r] = fmaf(e.w, wt3, accT[r]);
                accB[r] = fmaf(e.x, wb0, accB[r]);
                accB[r] = fmaf(e.y, wb1, accB[r]);
                accB[r] = fmaf(e.z, wb2, accB[r]);
                accB[r] = fmaf(e.w, wb3, accB[r]);
            }
        }
        #pragma unroll
        for (int r = 0; r < 8; ++r) {
            int row = rowbase + rg * 8 + r;
            Pp[(size_t)row * H1 + o] = accT[r];
            Qp[(size_t)row * H1 + o] = accB[r];
        }
    } else {
        float accB[8];
        #pragma unroll
        for (int r = 0; r < 8; ++r) accB[r] = 0.f;
        for (int d = 0; d < DHALF; d += 4) {
            float wb0 = W1[(DIM + d0 + d + 0) * H1 + o];
            float wb1 = W1[(DIM + d0 + d + 1) * H1 + o];
            float wb2 = W1[(DIM + d0 + d + 2) * H1 + o];
            float wb3 = W1[(DIM + d0 + d + 3) * H1 + o];
            #pragma unroll
            for (int r = 0; r < 8; ++r) {
                float4 e = *(const float4*)(lds_e + (rg * 8 + r) * DHALF + d);
                accB[r] = fmaf(e.x, wb0, accB[r]);
                accB[r] = fmaf(e.y, wb1, accB[r]);
                accB[r] = fmaf(e.z, wb2, accB[r]);
                accB[r] = fmaf(e.w, wb3, accB[r]);
            }
        }
        #pragma unroll
        for (int r = 0; r < 8; ++r) {
            int row = rowbase + rg * 8 + r;
            Qtp[(size_t)row * H1 + o] = accB[r];
        }
    }
}

// ---------------------------------------------------------------------------
// Kernel 2: sum the two partial slabs: ws[i] += ws[SLAB + i].
// 378 blocks x 256 threads x 8 floats = 774144 exactly.
// ---------------------------------------------------------------------------
__global__ __launch_bounds__(256) void reduce_kernel(float* __restrict__ ws)
{
    int i = (blockIdx.x * 256 + threadIdx.x) * 8;
    float4 a0 = *(const float4*)(ws + i);
    float4 a1 = *(const float4*)(ws + i + 4);
    float4 b0 = *(const float4*)(ws + SLAB + i);
    float4 b1 = *(const float4*)(ws + SLAB + i + 4);
    a0.x += b0.x; a0.y += b0.y; a0.z += b0.z; a0.w += b0.w;
    a1.x += b1.x; a1.y += b1.y; a1.z += b1.z; a1.w += b1.w;
    *(float4*)(ws + i)     = a0;
    *(float4*)(ws + i + 4) = a1;
}

// ---------------------------------------------------------------------------
// Kernel 3: score all 133,120 rows. One lane per row.
// __launch_bounds__(256, 2): VGPR budget 256 so acc[64] stays in registers
// (round-1 VGPR=44 showed the occupancy heuristic spilled acc to scratch).
// ---------------------------------------------------------------------------
__global__ __launch_bounds__(256, 2) void score_kernel(
    const float* __restrict__ P, const float* __restrict__ Q,
    const float* __restrict__ Qt,
    const float* __restrict__ b1, const float* __restrict__ W2,
    const float* __restrict__ b2, const float* __restrict__ W3,
    const float* __restrict__ b3,
    const int* __restrict__ h, const int* __restrict__ ns,
    float* __restrict__ out)
{
    const int gid  = blockIdx.x * blockDim.x + threadIdx.x;  // 0..133119
    const int b    = gid / NITEM;
    const int item = gid - b * NITEM;

    const float* Pr;
    const float* Qr;
    if (item == 0) {
        Pr = P  + (size_t)h[b] * H1;
        Qr = Qt + (size_t)b * H1;
    } else if (item <= KHALF) {
        Pr = P + (size_t)h[b] * H1;
        Qr = Q + (size_t)ns[b * 64 + (item - 1)] * H1;
    } else {
        Pr = P  + (size_t)ns[b * 64 + 32 + (item - 33)] * H1;
        Qr = Qt + (size_t)b * H1;
    }

    float acc[H2];
    #pragma unroll
    for (int j = 0; j < H2; ++j) acc[j] = 0.f;

    for (int o = 0; o < H1; o += 4) {
        float4 p4 = *(const float4*)(Pr + o);
        float4 q4 = *(const float4*)(Qr + o);
        float h0  = fmaxf(p4.x + q4.x + b1[o + 0], 0.f);
        float h1v = fmaxf(p4.y + q4.y + b1[o + 1], 0.f);
        float h2v = fmaxf(p4.z + q4.z + b1[o + 2], 0.f);
        float h3v = fmaxf(p4.w + q4.w + b1[o + 3], 0.f);
        #pragma unroll
        for (int j = 0; j < H2; ++j) {
            float a = acc[j];
            a = fmaf(h0,  W2[(o + 0) * H2 + j], a);
            a = fmaf(h1v, W2[(o + 1) * H2 + j], a);
            a = fmaf(h2v, W2[(o + 2) * H2 + j], a);
            a = fmaf(h3v, W2[(o + 3) * H2 + j], a);
            acc[j] = a;
        }
    }

    float outv = b3[0];
    #pragma unroll
    for (int j = 0; j < H2; ++j) {
        float hh = fmaxf(acc[j] + b2[j], 0.f);
        outv = fmaf(hh, W3[j], outv);
    }

    if (item == 0) out[b] = outv;
    else           out[BATCH + (size_t)b * 64 + (item - 1)] = outv;
}

extern "C" void kernel_launch(void* const* d_in, const int* in_sizes, int n_in,
                              void* d_out, int out_size, void* d_ws, size_t ws_size,
                              hipStream_t stream) {
    const float* embed = (const float*)d_in[0];
    const float* W1    = (const float*)d_in[1];
    const float* b1    = (const float*)d_in[2];
    const float* W2    = (const float*)d_in[3];
    const float* b2    = (const float*)d_in[4];
    const float* W3    = (const float*)d_in[5];
    const float* b3    = (const float*)d_in[6];
    const int*   h     = (const int*)d_in[7];
    const int*   t     = (const int*)d_in[8];
    const int*   ns    = (const int*)d_in[9];
    float* out = (float*)d_out;

    float* ws = (float*)d_ws;        // 2 slabs x 774,144 floats = 6.2 MB
    float* P  = ws;                  // 2000*128
    float* Q  = P + NDRUG * H1;      // 2000*128
    float* Qt = Q + NDRUG * H1;      // 2048*128

    dim3 grid1(253, 2);
    layer1_partial<<<grid1, 256, 0, stream>>>(embed, W1, t, ws);
    reduce_kernel<<<SLAB / (256 * 8), 256, 0, stream>>>(ws);

    const int nrows = BATCH * NITEM;     // 133120, divisible by 256
    score_kernel<<<nrows / 256, 256, 0, stream>>>(P, Q, Qt, b1, W2, b2, W3, b3,
                                                  h, ns, out);
}

// Round 3
// 139.201 us; speedup vs baseline: 1.4906x; 1.3195x over previous
//
#include <hip/hip_runtime.h>

#define NNODES 20000
#define DIM    512
#define BATCH  2048
#define NDRUG  2000
#define H1     128
#define H2     64
#define NITEM  65        // 1 pos + 64 neg per sample
#define DQ     256       // d-columns per slab (2 slabs)
#define SLAB   774144    // floats per partial slab: (2000+2000+2048)*128

typedef __attribute__((ext_vector_type(8))) short short8;
typedef __attribute__((ext_vector_type(4))) float floatx4;

// f32 -> bf16 with round-to-nearest-even (bit trick; inputs are finite)
__device__ inline unsigned short f2bf(float x) {
    union { float f; unsigned u; } v; v.f = x;
    unsigned r = v.u + 0x7fffu + ((v.u >> 16) & 1u);
    return (unsigned short)(r >> 16);
}

// ---------------------------------------------------------------------------
// Kernel A: prepack W2 (128x64 f32) into bf16 B-fragment lane order for
// mfma_f32_16x16x32_bf16. Tile (kt,nt): lane L holds B[k=kt*32+(L>>4)*8+j]
// [n=nt*16+(L&15)], j=0..7. Stored so score loads are coalesced float4s.
// ---------------------------------------------------------------------------
__global__ void prep_w2(const float* __restrict__ W2, float* __restrict__ ws)
{
    short8* dst = (short8*)(ws + 2 * (size_t)SLAB);
    const int lane = threadIdx.x & 63;
    const int n = lane & 15, q = lane >> 4;
    #pragma unroll
    for (int kt = 0; kt < 4; ++kt) {
        #pragma unroll
        for (int nt = 0; nt < 4; ++nt) {
            short8 v;
            #pragma unroll
            for (int j = 0; j < 8; ++j) {
                int k = kt * 32 + q * 8 + j;
                v[j] = (short)f2bf(W2[k * H2 + nt * 16 + n]);
            }
            dst[(kt * 4 + nt) * 64 + lane] = v;
        }
    }
}

// ---------------------------------------------------------------------------
// Kernel B: layer-1 partial GEMMs (f32 VALU), D split in 2 slabs.
// grid (253, 2), block 512 = 128 outputs x 4 row-groups (4 rows each).
// x<125: P+Q for 16 drug rows. x>=125: Qt for 16 gathered t rows.
// Explicit 1-iter W1 register prefetch breaks the load->FMA serial chain.
// ---------------------------------------------------------------------------
__global__ __launch_bounds__(512) void layer1_partial(
    const float* __restrict__ embed, const float* __restrict__ W1,
    const int* __restrict__ t, float* __restrict__ ws)
{
    __shared__ float lds_e[16 * DQ];     // 16 KB
    const int s   = blockIdx.y;
    const int blk = blockIdx.x;
    const bool isPQ = blk < 125;
    const int rowbase = isPQ ? blk * 16 : (blk - 125) * 16;
    const int o  = threadIdx.x & 127;
    const int rg = threadIdx.x >> 7;     // 0..3 -> rows rg*4 .. rg*4+3
    const int d0 = s * DQ;

    // Stage 16 rows x 256 cols: 1024 float4 / 512 threads = 2 each
    #pragma unroll
    for (int i = 0; i < 2; ++i) {
        int idx = i * 512 + threadIdx.x;
        int r = idx >> 6, c4 = idx & 63;
        int grow = isPQ ? (rowbase + r) : t[rowbase + r];
        *(float4*)(lds_e + r * DQ + c4 * 4) =
            *(const float4*)(embed + (size_t)grow * DIM + d0 + c4 * 4);
    }
    __syncthreads();

    float* Pp  = ws + (size_t)s * SLAB;
    float* Qp  = Pp + NDRUG * H1;
    float* Qtp = Qp + NDRUG * H1;

    if (isPQ) {
        float accT[4] = {0.f,0.f,0.f,0.f}, accB[4] = {0.f,0.f,0.f,0.f};
        float wT[4], wB[4];
        #pragma unroll
        for (int e = 0; e < 4; ++e) {
            wT[e] = W1[(d0 + e) * H1 + o];
            wB[e] = W1[(DIM + d0 + e) * H1 + o];
        }
        for (int d = 0; d < DQ; d += 4) {
            const int dn = (d + 4 < DQ) ? d + 4 : d;   // last iter: dummy reload
            float nT[4], nB[4];
            #pragma unroll
            for (int e = 0; e < 4; ++e) {
                nT[e] = W1[(d0 + dn + e) * H1 + o];
                nB[e] = W1[(DIM + d0 + dn + e) * H1 + o];
            }
            #pragma unroll
            for (int r = 0; r < 4; ++r) {
                float4 ev = *(const float4*)(lds_e + (rg * 4 + r) * DQ + d);
                accT[r] = fmaf(ev.x, wT[0], accT[r]);
                accT[r] = fmaf(ev.y, wT[1], accT[r]);
                accT[r] = fmaf(ev.z, wT[2], accT[r]);
                accT[r] = fmaf(ev.w, wT[3], accT[r]);
                accB[r] = fmaf(ev.x, wB[0], accB[r]);
                accB[r] = fmaf(ev.y, wB[1], accB[r]);
                accB[r] = fmaf(ev.z, wB[2], accB[r]);
                accB[r] = fmaf(ev.w, wB[3], accB[r]);
            }
            #pragma unroll
            for (int e = 0; e < 4; ++e) { wT[e] = nT[e]; wB[e] = nB[e]; }
        }
        #pragma unroll
        for (int r = 0; r < 4; ++r) {
            int row = rowbase + rg * 4 + r;
            Pp[(size_t)row * H1 + o] = accT[r];
            Qp[(size_t)row * H1 + o] = accB[r];
        }
    } else {
        float accB[4] = {0.f,0.f,0.f,0.f};
        float wB[4];
        #pragma unroll
        for (int e = 0; e < 4; ++e) wB[e] = W1[(DIM + d0 + e) * H1 + o];
        for (int d = 0; d < DQ; d += 4) {
            const int dn = (d + 4 < DQ) ? d + 4 : d;
            float nB[4];
            #pragma unroll
            for (int e = 0; e < 4; ++e) nB[e] = W1[(DIM + d0 + dn + e) * H1 + o];
            #pragma unroll
            for (int r = 0; r < 4; ++r) {
                float4 ev = *(const float4*)(lds_e + (rg * 4 + r) * DQ + d);
                accB[r] = fmaf(ev.x, wB[0], accB[r]);
                accB[r] = fmaf(ev.y, wB[1], accB[r]);
                accB[r] = fmaf(ev.z, wB[2], accB[r]);
                accB[r] = fmaf(ev.w, wB[3], accB[r]);
            }
            #pragma unroll
            for (int e = 0; e < 4; ++e) wB[e] = nB[e];
        }
        #pragma unroll
        for (int r = 0; r < 4; ++r) {
            int row = rowbase + rg * 4 + r;
            Qtp[(size_t)row * H1 + o] = accB[r];
        }
    }
}

// ---------------------------------------------------------------------------
// Kernel C: sum the two partial slabs: ws[i] += ws[SLAB + i].
// ---------------------------------------------------------------------------
__global__ __launch_bounds__(256) void reduce_kernel(float* __restrict__ ws)
{
    int i = (blockIdx.x * 256 + threadIdx.x) * 8;
    float4 a0 = *(const float4*)(ws + i);
    float4 a1 = *(const float4*)(ws + i + 4);
    float4 b0 = *(const float4*)(ws + SLAB + i);
    float4 b1v = *(const float4*)(ws + SLAB + i + 4);
    a0.x += b0.x; a0.y += b0.y; a0.z += b0.z; a0.w += b0.w;
    a1.x += b1v.x; a1.y += b1v.y; a1.z += b1v.z; a1.w += b1v.w;
    *(float4*)(ws + i)     = a0;
    *(float4*)(ws + i + 4) = a1;
}

// ---------------------------------------------------------------------------
// Kernel D: score via MFMA. One wave per 16 rows (tile). Layer-2 GEMM as
// 4 kt x 4 nt mfma_f32_16x16x32_bf16; A = h1 built on the fly (f32 relu ->
// bf16 RNE), B = prepacked W2 fragments. Epilogue: relu+W3 dot in C-layout
// (lane holds rows q*4+reg, col n=lane&15), 16-lane shuffle reduce.
// ---------------------------------------------------------------------------
__global__ __launch_bounds__(256) void score_mfma(
    const float* __restrict__ ws,
    const float* __restrict__ b1, const float* __restrict__ b2,
    const float* __restrict__ W3, const float* __restrict__ b3,
    const int* __restrict__ h, const int* __restrict__ ns,
    float* __restrict__ out)
{
    const float* P  = ws;
    const float* Q  = ws + NDRUG * H1;
    const float* Qt = Q + NDRUG * H1;
    const short8* W2f = (const short8*)(ws + 2 * (size_t)SLAB);

    const int lane = threadIdx.x & 63;
    const int wv   = threadIdx.x >> 6;
    const int tile = blockIdx.x * 4 + wv;      // 0..8319
    const int n = lane & 15, q = lane >> 4;

    // This lane supplies A rows m = n for sample gid = tile*16 + n
    const int sg   = tile * 16 + n;
    const int b    = sg / NITEM;
    const int item = sg - b * NITEM;
    const float *Pr, *Qr;
    if (item == 0)       { Pr = P + h[b] * H1;                      Qr = Qt + b * H1; }
    else if (item <= 32) { Pr = P + h[b] * H1;                      Qr = Q + ns[b * 64 + item - 1] * H1; }
    else                 { Pr = P + ns[b * 64 + 32 + item - 33] * H1; Qr = Qt + b * H1; }

    floatx4 acc[4];
    #pragma unroll
    for (int nt = 0; nt < 4; ++nt) acc[nt] = (floatx4){0.f, 0.f, 0.f, 0.f};

    #pragma unroll
    for (int kt = 0; kt < 4; ++kt) {
        const int kb = kt * 32 + q * 8;
        float4 p0 = *(const float4*)(Pr + kb);
        float4 p1 = *(const float4*)(Pr + kb + 4);
        float4 q0 = *(const float4*)(Qr + kb);
        float4 q1 = *(const float4*)(Qr + kb + 4);
        float4 c0 = *(const float4*)(b1 + kb);
        float4 c1 = *(const float4*)(b1 + kb + 4);
        short8 af;
        af[0] = (short)f2bf(fmaxf(p0.x + q0.x + c0.x, 0.f));
        af[1] = (short)f2bf(fmaxf(p0.y + q0.y + c0.y, 0.f));
        af[2] = (short)f2bf(fmaxf(p0.z + q0.z + c0.z, 0.f));
        af[3] = (short)f2bf(fmaxf(p0.w + q0.w + c0.w, 0.f));
        af[4] = (short)f2bf(fmaxf(p1.x + q1.x + c1.x, 0.f));
        af[5] = (short)f2bf(fmaxf(p1.y + q1.y + c1.y, 0.f));
        af[6] = (short)f2bf(fmaxf(p1.z + q1.z + c1.z, 0.f));
        af[7] = (short)f2bf(fmaxf(p1.w + q1.w + c1.w, 0.f));
        #pragma unroll
        for (int nt = 0; nt < 4; ++nt) {
            short8 bf = W2f[(kt * 4 + nt) * 64 + lane];
            acc[nt] = __builtin_amdgcn_mfma_f32_16x16x32_bf16(af, bf, acc[nt], 0, 0, 0);
        }
    }

    // Epilogue: lane holds D[row = q*4+reg][col = n + 16*nt]
    float part[4];
    #pragma unroll
    for (int reg = 0; reg < 4; ++reg) {
        float sum = 0.f;
        #pragma unroll
        for (int nt = 0; nt < 4; ++nt) {
            int j = nt * 16 + n;
            sum = fmaf(fmaxf(acc[nt][reg] + b2[j], 0.f), W3[j], sum);
        }
        part[reg] = sum;
    }
    #pragma unroll
    for (int m = 1; m < 16; m <<= 1) {
        #pragma unroll
        for (int reg = 0; reg < 4; ++reg)
            part[reg] += __shfl_xor(part[reg], m, 64);
    }
    if (n == 0) {
        const float base3 = b3[0];
        #pragma unroll
        for (int reg = 0; reg < 4; ++reg) {
            int gid = tile * 16 + q * 4 + reg;
            int bb  = gid / NITEM;
            int it  = gid - bb * NITEM;
            float val = part[reg] + base3;
            if (it == 0) out[bb] = val;
            else         out[BATCH + bb * 64 + (it - 1)] = val;
        }
    }
}

extern "C" void kernel_launch(void* const* d_in, const int* in_sizes, int n_in,
                              void* d_out, int out_size, void* d_ws, size_t ws_size,
                              hipStream_t stream) {
    const float* embed = (const float*)d_in[0];
    const float* W1    = (const float*)d_in[1];
    const float* b1    = (const float*)d_in[2];
    const float* W2    = (const float*)d_in[3];
    const float* b2    = (const float*)d_in[4];
    const float* W3    = (const float*)d_in[5];
    const float* b3    = (const float*)d_in[6];
    const int*   h     = (const int*)d_in[7];
    const int*   t     = (const int*)d_in[8];
    const int*   ns    = (const int*)d_in[9];
    float* out = (float*)d_out;
    float* ws  = (float*)d_ws;   // slab0 | slab1 | W2 bf16 frags (8 KB)

    prep_w2<<<1, 64, 0, stream>>>(W2, ws);

    dim3 grid1(253, 2);
    layer1_partial<<<grid1, 512, 0, stream>>>(embed, W1, t, ws);
    reduce_kernel<<<SLAB / (256 * 8), 256, 0, stream>>>(ws);

    score_mfma<<<(BATCH * NITEM) / 64, 256, 0, stream>>>(ws, b1, b2, W3, b3,
                                                         h, ns, out);
}

// Round 4
// 127.189 us; speedup vs baseline: 1.6314x; 1.0944x over previous
//
#include <hip/hip_runtime.h>

#define DIM    512
#define BATCH  2048
#define NDRUG  2000
#define H1     128
#define H2     64
#define NITEM  65        // 1 pos + 64 neg per sample
#define SLAB   774144    // floats per slab: (2000 P + 2000 Q + 2048 Qt) * 128
// ws float offsets
#define W2F_OFF (4 * SLAB)            // 16 KB of W2 bf16 fragments
#define W1F_OFF (W2F_OFF + 4096)      // 262 KB of W1 bf16 fragments
#define X1_OFF  (W1F_OFF + 65536)     // drug rows bf16: 2000 x 512
#define X2_OFF  (X1_OFF + 512000)     // gathered t rows bf16: 2048 x 512

typedef __attribute__((ext_vector_type(8))) short short8;
typedef __attribute__((ext_vector_type(4))) float floatx4;

// f32 -> bf16 round-to-nearest-even (inputs finite)
__device__ inline unsigned short f2bf(float x) {
    union { float f; unsigned u; } v; v.f = x;
    unsigned r = v.u + 0x7fffu + ((v.u >> 16) & 1u);
    return (unsigned short)(r >> 16);
}

__device__ inline short8 cvt8(const float* __restrict__ src) {
    float4 a = *(const float4*)src, b = *(const float4*)(src + 4);
    short8 v;
    v[0] = (short)f2bf(a.x); v[1] = (short)f2bf(a.y);
    v[2] = (short)f2bf(a.z); v[3] = (short)f2bf(a.w);
    v[4] = (short)f2bf(b.x); v[5] = (short)f2bf(b.y);
    v[6] = (short)f2bf(b.z); v[7] = (short)f2bf(b.w);
    return v;
}

// ---------------------------------------------------------------------------
// Kernel 1: all packing. 256 blocks x 256 threads.
//  blk [0,125):   X1  = bf16(embed[0:2000])              (128000 short8 units)
//  blk [125,253): X2  = bf16(embed[t[0:2048]])           (131072 units)
//  blk [253,255): W1f = B-fragments of W1 (both halves)  (16384 lane-items)
//  blk 255:       W2f = B-fragments of W2                (1024 lane-items)
// B-frag layout (mfma_f32_16x16x32_bf16): lane L holds
//   B[k = kt*32 + (L>>4)*8 + j][n = nt*16 + (L&15)], j = 0..7.
// ---------------------------------------------------------------------------
__global__ __launch_bounds__(256) void prep(
    const float* __restrict__ embed, const float* __restrict__ W1,
    const float* __restrict__ W2, const int* __restrict__ t,
    float* __restrict__ ws)
{
    const int blk = blockIdx.x, tid = threadIdx.x;
    if (blk < 125) {
        short8* X1 = (short8*)(ws + X1_OFF);
        #pragma unroll
        for (int i = 0; i < 4; ++i) {
            int u = blk * 1024 + i * 256 + tid;       // < 128000
            int row = u >> 6, c = u & 63;
            X1[u] = cvt8(embed + (size_t)row * DIM + c * 8);
        }
    } else if (blk < 253) {
        short8* X2 = (short8*)(ws + X2_OFF);
        #pragma unroll
        for (int i = 0; i < 4; ++i) {
            int u = (blk - 125) * 1024 + i * 256 + tid;  // < 131072
            int row = u >> 6, c = u & 63;
            X2[u] = cvt8(embed + (size_t)t[row] * DIM + c * 8);
        }
    } else if (blk < 255) {
        short8* W1f = (short8*)(ws + W1F_OFF);
        #pragma unroll
        for (int i = 0; i < 32; ++i) {
            int item = (blk - 253) * 8192 + i * 256 + tid;  // < 16384
            int frag = item >> 6, lane = item & 63;
            int half = frag >> 7, ktot = (frag >> 3) & 15, nt = frag & 7;
            int n = lane & 15, q = lane >> 4;
            short8 v;
            #pragma unroll
            for (int j = 0; j < 8; ++j) {
                int k = half * DIM + ktot * 32 + q * 8 + j;
                v[j] = (short)f2bf(W1[k * H1 + nt * 16 + n]);
            }
            W1f[item] = v;
        }
    } else {
        short8* W2f = (short8*)(ws + W2F_OFF);
        #pragma unroll
        for (int i = 0; i < 4; ++i) {
            int item = i * 256 + tid;                 // < 1024
            int frag = item >> 6, lane = item & 63;
            int kt = frag >> 2, nt = frag & 3;
            int n = lane & 15, q = lane >> 4;
            short8 v;
            #pragma unroll
            for (int j = 0; j < 8; ++j)
                v[j] = (short)f2bf(W2[(kt * 32 + q * 8 + j) * H2 + nt * 16 + n]);
            W2f[item] = v;
        }
    }
}

// ---------------------------------------------------------------------------
// Kernel 2: layer-1 via MFMA, split-K=4. 3024 waves total, one wave =
// 16 rows x 64 cols x K=128 (4 kt x 4 nt = 16 MFMAs).
//  w < 2000:  PQ. rt = w>>4; cg = (w>>2)&3 (0/1 -> P cols 0-63/64-127,
//             2/3 -> Q cols 0-63/64-127); kc = w&3.
//  w >= 2000: Qt. rt = (w-2000)>>3; cg = (w>>2)&1 -> Qt cols; kc = w&3.
// Partial results go to slab kc; reduce4 sums the 4 slabs into slab 0.
// ---------------------------------------------------------------------------
__global__ __launch_bounds__(256) void layer1_mfma(float* __restrict__ ws)
{
    const short8* W1f = (const short8*)(ws + W1F_OFF);
    const int lane = threadIdx.x & 63;
    const int w    = blockIdx.x * 4 + (threadIdx.x >> 6);   // 0..3023
    const int n = lane & 15, q = lane >> 4;

    const short8* Xrow;
    float* obase;
    int half, ntsel, kc;
    if (w < 2000) {
        int rt = w >> 4, rem = w & 15, cg = rem >> 2;
        kc = rem & 3;
        Xrow = (const short8*)(ws + X1_OFF) + (size_t)(rt * 16 + n) * 64 + kc * 16;
        half  = cg >> 1;
        ntsel = (cg & 1) * 4;
        obase = ws + (size_t)kc * SLAB + half * (NDRUG * H1)
                   + (size_t)(rt * 16) * H1 + (cg & 1) * 64;
    } else {
        int w2 = w - 2000;
        int rt = w2 >> 3, rem = w2 & 7, cg = rem >> 2;
        kc = rem & 3;
        Xrow = (const short8*)(ws + X2_OFF) + (size_t)(rt * 16 + n) * 64 + kc * 16;
        half  = 1;
        ntsel = cg * 4;
        obase = ws + (size_t)kc * SLAB + 2 * (NDRUG * H1)
                   + (size_t)(rt * 16) * H1 + cg * 64;
    }

    floatx4 acc[4];
    #pragma unroll
    for (int nt = 0; nt < 4; ++nt) acc[nt] = (floatx4){0.f, 0.f, 0.f, 0.f};

    #pragma unroll
    for (int kt = 0; kt < 4; ++kt) {
        short8 af = Xrow[kt * 4 + q];     // A[m=n][k = kc*128 + kt*32 + q*8 ..]
        #pragma unroll
        for (int nt = 0; nt < 4; ++nt) {
            short8 bf = W1f[(size_t)((half * 16 + kc * 4 + kt) * 8 + ntsel + nt) * 64 + lane];
            acc[nt] = __builtin_amdgcn_mfma_f32_16x16x32_bf16(af, bf, acc[nt], 0, 0, 0);
        }
    }

    // C layout: lane holds D[row = q*4+reg][col = nt*16 + n]
    #pragma unroll
    for (int nt = 0; nt < 4; ++nt)
        #pragma unroll
        for (int reg = 0; reg < 4; ++reg)
            obase[(q * 4 + reg) * H1 + nt * 16 + n] = acc[nt][reg];
}

// ---------------------------------------------------------------------------
// Kernel 3: sum 4 partial slabs into slab 0. 378 blocks x 256 x 8 floats.
// ---------------------------------------------------------------------------
__global__ __launch_bounds__(256) void reduce4(float* __restrict__ ws)
{
    int i = (blockIdx.x * 256 + threadIdx.x) * 8;
    #pragma unroll
    for (int half = 0; half < 2; ++half) {
        int o = i + half * 4;
        float4 a = *(const float4*)(ws + o);
        float4 b = *(const float4*)(ws + SLAB + o);
        float4 c = *(const float4*)(ws + 2 * SLAB + o);
        float4 d = *(const float4*)(ws + 3 * SLAB + o);
        a.x += b.x + c.x + d.x;  a.y += b.y + c.y + d.y;
        a.z += b.z + c.z + d.z;  a.w += b.w + c.w + d.w;
        *(float4*)(ws + o) = a;
    }
}

// ---------------------------------------------------------------------------
// Kernel 4: score via MFMA (unchanged from round 3, passed). One wave per
// 16 rows; layer-2 as 4kt x 4nt mfma_f32_16x16x32_bf16; A = relu(P+Q+b1)
// built on the fly; B = prepacked W2f. Epilogue relu+W3 in C-layout +
// 16-lane shuffle reduce.
// ---------------------------------------------------------------------------
__global__ __launch_bounds__(256) void score_mfma(
    const float* __restrict__ ws,
    const float* __restrict__ b1, const float* __restrict__ b2,
    const float* __restrict__ W3, const float* __restrict__ b3,
    const int* __restrict__ h, const int* __restrict__ ns,
    float* __restrict__ out)
{
    const float* P  = ws;
    const float* Q  = ws + NDRUG * H1;
    const float* Qt = Q + NDRUG * H1;
    const short8* W2f = (const short8*)(ws + W2F_OFF);

    const int lane = threadIdx.x & 63;
    const int wv   = threadIdx.x >> 6;
    const int tile = blockIdx.x * 4 + wv;      // 0..8319
    const int n = lane & 15, q = lane >> 4;

    const int sg   = tile * 16 + n;
    const int b    = sg / NITEM;
    const int item = sg - b * NITEM;
    const float *Pr, *Qr;
    if (item == 0)       { Pr = P + h[b] * H1;                        Qr = Qt + b * H1; }
    else if (item <= 32) { Pr = P + h[b] * H1;                        Qr = Q + ns[b * 64 + item - 1] * H1; }
    else                 { Pr = P + ns[b * 64 + 32 + item - 33] * H1; Qr = Qt + b * H1; }

    floatx4 acc[4];
    #pragma unroll
    for (int nt = 0; nt < 4; ++nt) acc[nt] = (floatx4){0.f, 0.f, 0.f, 0.f};

    #pragma unroll
    for (int kt = 0; kt < 4; ++kt) {
        const int kb = kt * 32 + q * 8;
        float4 p0 = *(const float4*)(Pr + kb);
        float4 p1 = *(const float4*)(Pr + kb + 4);
        float4 q0 = *(const float4*)(Qr + kb);
        float4 q1 = *(const float4*)(Qr + kb + 4);
        float4 c0 = *(const float4*)(b1 + kb);
        float4 c1 = *(const float4*)(b1 + kb + 4);
        short8 af;
        af[0] = (short)f2bf(fmaxf(p0.x + q0.x + c0.x, 0.f));
        af[1] = (short)f2bf(fmaxf(p0.y + q0.y + c0.y, 0.f));
        af[2] = (short)f2bf(fmaxf(p0.z + q0.z + c0.z, 0.f));
        af[3] = (short)f2bf(fmaxf(p0.w + q0.w + c0.w, 0.f));
        af[4] = (short)f2bf(fmaxf(p1.x + q1.x + c1.x, 0.f));
        af[5] = (short)f2bf(fmaxf(p1.y + q1.y + c1.y, 0.f));
        af[6] = (short)f2bf(fmaxf(p1.z + q1.z + c1.z, 0.f));
        af[7] = (short)f2bf(fmaxf(p1.w + q1.w + c1.w, 0.f));
        #pragma unroll
        for (int nt = 0; nt < 4; ++nt) {
            short8 bf = W2f[(kt * 4 + nt) * 64 + lane];
            acc[nt] = __builtin_amdgcn_mfma_f32_16x16x32_bf16(af, bf, acc[nt], 0, 0, 0);
        }
    }

    float part[4];
    #pragma unroll
    for (int reg = 0; reg < 4; ++reg) {
        float sum = 0.f;
        #pragma unroll
        for (int nt = 0; nt < 4; ++nt) {
            int j = nt * 16 + n;
            sum = fmaf(fmaxf(acc[nt][reg] + b2[j], 0.f), W3[j], sum);
        }
        part[reg] = sum;
    }
    #pragma unroll
    for (int m = 1; m < 16; m <<= 1) {
        #pragma unroll
        for (int reg = 0; reg < 4; ++reg)
            part[reg] += __shfl_xor(part[reg], m, 64);
    }
    if (n == 0) {
        const float base3 = b3[0];
        #pragma unroll
        for (int reg = 0; reg < 4; ++reg) {
            int gid = tile * 16 + q * 4 + reg;
            int bb  = gid / NITEM;
            int it  = gid - bb * NITEM;
            float val = part[reg] + base3;
            if (it == 0) out[bb] = val;
            else         out[BATCH + bb * 64 + (it - 1)] = val;
        }
    }
}

extern "C" void kernel_launch(void* const* d_in, const int* in_sizes, int n_in,
                              void* d_out, int out_size, void* d_ws, size_t ws_size,
                              hipStream_t stream) {
    const float* embed = (const float*)d_in[0];
    const float* W1    = (const float*)d_in[1];
    const float* b1    = (const float*)d_in[2];
    const float* W2    = (const float*)d_in[3];
    const float* b2    = (const float*)d_in[4];
    const float* W3    = (const float*)d_in[5];
    const float* b3    = (const float*)d_in[6];
    const int*   h     = (const int*)d_in[7];
    const int*   t     = (const int*)d_in[8];
    const int*   ns    = (const int*)d_in[9];
    float* out = (float*)d_out;
    float* ws  = (float*)d_ws;   // 4 slabs | W2f | W1f | X1 | X2  (~16.8 MB)

    prep<<<256, 256, 0, stream>>>(embed, W1, W2, t, ws);
    layer1_mfma<<<756, 256, 0, stream>>>(ws);          // 3024 waves
    reduce4<<<SLAB / (256 * 8), 256, 0, stream>>>(ws); // 378 blocks
    score_mfma<<<(BATCH * NITEM) / 64, 256, 0, stream>>>(ws, b1, b2, W3, b3,
                                                         h, ns, out);
}

// Round 6
// 120.183 us; speedup vs baseline: 1.7264x; 1.0583x over previous
//
#include <hip/hip_runtime.h>

#define DIM    512
#define BATCH  2048
#define NDRUG  2000
#define H1     128
#define H2     64
#define NITEM  65        // 1 pos + 64 neg per sample
#define SLAB   774144    // floats: P 2000x128 | Q 2000x128 | Qt 2048x128
// ws float offsets
#define W2F_OFF  (SLAB)               // 16 KB  W2 bf16 B-fragments
#define W1F_OFF  (W2F_OFF + 4096)     // 256 KB W1 bf16 B-fragments
#define X1_OFF   (W1F_OFF + 65536)    // 2 MB   drug rows bf16 (2000 x 512)
#define X2_OFF   (X1_OFF + 512000)    // 2 MB   gathered t rows bf16 (2048 x 512)

typedef __attribute__((ext_vector_type(8))) short short8;
typedef __attribute__((ext_vector_type(4))) float floatx4;

// f32 -> bf16 RNE (bit trick; inputs finite). Proven in rounds 3-4.
__device__ inline unsigned f2bf(float x) {
    union { float f; unsigned u; } v; v.f = x;
    unsigned r = v.u + 0x7fffu + ((v.u >> 16) & 1u);
    return r >> 16;
}

// pack two f32 -> bf16x2 (a in low 16 bits)
__device__ inline unsigned pkbf(float a, float b) {
    return f2bf(a) | (f2bf(b) << 16);
}

__device__ inline short8 cvt8(const float* __restrict__ src) {
    float4 a = *(const float4*)src, b = *(const float4*)(src + 4);
    union { short8 s; unsigned u[4]; } v;
    v.u[0] = pkbf(a.x, a.y); v.u[1] = pkbf(a.z, a.w);
    v.u[2] = pkbf(b.x, b.y); v.u[3] = pkbf(b.z, b.w);
    return v.s;
}

// ---------------------------------------------------------------------------
// Kernel 1: packing. 318 blocks x 256.
//  blk [0,125):   X1 = bf16(embed[0:2000])     125 blk x 1024 short8 units
//  blk [125,253): X2 = bf16(embed[t[0:2048]])  128 blk x 1024 units
//  blk [253,317): W1f B-fragments              64 blk x 256 lane-items
//  blk 317:       W2f B-fragments              1 blk x 1024 lane-items
// B-frag layout (mfma_f32_16x16x32_bf16): lane L holds
//   B[k = kt*32 + (L>>4)*8 + j][n = nt*16 + (L&15)], j = 0..7.
// ---------------------------------------------------------------------------
__global__ __launch_bounds__(256) void prep(
    const float* __restrict__ embed, const float* __restrict__ W1,
    const float* __restrict__ W2, const int* __restrict__ t,
    float* __restrict__ ws)
{
    const int blk = blockIdx.x, tid = threadIdx.x;
    if (blk < 125) {
        short8* X1 = (short8*)(ws + X1_OFF);
        #pragma unroll
        for (int i = 0; i < 4; ++i) {
            int u = blk * 1024 + i * 256 + tid;        // < 128000
            int row = u >> 6, c = u & 63;
            X1[u] = cvt8(embed + (size_t)row * DIM + c * 8);
        }
    } else if (blk < 253) {
        short8* X2 = (short8*)(ws + X2_OFF);
        #pragma unroll
        for (int i = 0; i < 4; ++i) {
            int u = (blk - 125) * 1024 + i * 256 + tid;  // < 131072
            int row = u >> 6, c = u & 63;
            X2[u] = cvt8(embed + (size_t)t[row] * DIM + c * 8);
        }
    } else if (blk < 317) {
        short8* W1f = (short8*)(ws + W1F_OFF);
        int item = (blk - 253) * 256 + tid;            // < 16384
        int frag = item >> 6, lane = item & 63;
        int half = frag >> 7, kt = (frag >> 3) & 15, nt = frag & 7;
        int n = lane & 15, q = lane >> 4;
        short8 v;
        #pragma unroll
        for (int j = 0; j < 8; ++j) {
            int k = half * DIM + kt * 32 + q * 8 + j;
            v[j] = (short)f2bf(W1[k * H1 + nt * 16 + n]);
        }
        W1f[item] = v;
    } else {
        short8* W2f = (short8*)(ws + W2F_OFF);
        #pragma unroll
        for (int i = 0; i < 4; ++i) {
            int item = i * 256 + tid;                  // < 1024
            int frag = item >> 6, lane = item & 63;
            int kt = frag >> 2, nt = frag & 3;
            int n = lane & 15, q = lane >> 4;
            short8 v;
            #pragma unroll
            for (int j = 0; j < 8; ++j)
                v[j] = (short)f2bf(W2[(kt * 32 + q * 8 + j) * H2 + nt * 16 + n]);
            W2f[item] = v;
        }
    }
}

// ---------------------------------------------------------------------------
// Kernel 2: layer-1 via MFMA, full K=512 per wave (no split-K, no reduce).
// One wave = 16 rows x 16 cols, 16 MFMAs (2 interleaved accumulators).
//  w < 2000:  rt = w>>4, cv = w&15. cv<8 -> P cols nt=cv (half 0);
//             cv>=8 -> Q cols nt=cv-8 (half 1, +b1 fold).
//  w >= 2000: Qt. rt = (w-2000)>>3, nt = (w-2000)&7, half 1, +b1 fold.
// b1 folded into tail tables (Q, Qt) so score skips it.
// ---------------------------------------------------------------------------
__global__ __launch_bounds__(256) void layer1_mfma(
    float* __restrict__ ws, const float* __restrict__ b1)
{
    const short8* W1f = (const short8*)(ws + W1F_OFF);
    const int lane = threadIdx.x & 63;
    const int w    = blockIdx.x * 4 + (threadIdx.x >> 6);   // 0..3023
    const int n = lane & 15, q = lane >> 4;

    const short8* Xrow;
    float* obase;
    int half, nt;
    bool tail;
    if (w < 2000) {
        int rt = w >> 4, cv = w & 15;
        tail = cv >= 8;
        nt   = cv & 7;
        half = tail ? 1 : 0;
        Xrow = (const short8*)(ws + X1_OFF) + (size_t)(rt * 16 + n) * 64;
        obase = ws + (tail ? NDRUG * H1 : 0) + (size_t)(rt * 16) * H1 + nt * 16;
    } else {
        int w2 = w - 2000;
        int rt = w2 >> 3;
        nt   = w2 & 7;
        half = 1;
        tail = true;
        Xrow = (const short8*)(ws + X2_OFF) + (size_t)(rt * 16 + n) * 64;
        obase = ws + 2 * (NDRUG * H1) + (size_t)(rt * 16) * H1 + nt * 16;
    }

    floatx4 acc0 = (floatx4){0.f, 0.f, 0.f, 0.f};
    floatx4 acc1 = (floatx4){0.f, 0.f, 0.f, 0.f};
    const int fbase = (half * 16) * 8 + nt;
    #pragma unroll
    for (int kt = 0; kt < 16; kt += 2) {
        short8 a0 = Xrow[kt * 4 + q];
        short8 a1 = Xrow[(kt + 1) * 4 + q];
        short8 b0 = W1f[(size_t)(fbase + kt * 8) * 64 + lane];
        short8 b1f = W1f[(size_t)(fbase + (kt + 1) * 8) * 64 + lane];
        acc0 = __builtin_amdgcn_mfma_f32_16x16x32_bf16(a0, b0, acc0, 0, 0, 0);
        acc1 = __builtin_amdgcn_mfma_f32_16x16x32_bf16(a1, b1f, acc1, 0, 0, 0);
    }

    const float badd = tail ? b1[nt * 16 + n] : 0.f;
    // C layout: lane holds D[row = q*4+reg][col = n]
    #pragma unroll
    for (int reg = 0; reg < 4; ++reg)
        obase[(q * 4 + reg) * H1 + n] = acc0[reg] + acc1[reg] + badd;
}

// ---------------------------------------------------------------------------
// Kernel 3: score via MFMA. One wave per 16 rows; layer-2 as 4kt x 4nt
// mfma_f32_16x16x32_bf16; A = relu(P + Qtail) built on the fly (b1 already
// folded into Q/Qt); B = prepacked W2f. Epilogue relu+W3 in C-layout +
// 16-lane shuffle reduce.
// ---------------------------------------------------------------------------
__global__ __launch_bounds__(256) void score_mfma(
    const float* __restrict__ ws,
    const float* __restrict__ b2, const float* __restrict__ W3,
    const float* __restrict__ b3,
    const int* __restrict__ h, const int* __restrict__ ns,
    float* __restrict__ out)
{
    const float* P  = ws;
    const float* Q  = ws + NDRUG * H1;
    const float* Qt = Q + NDRUG * H1;
    const short8* W2f = (const short8*)(ws + W2F_OFF);

    const int lane = threadIdx.x & 63;
    const int wv   = threadIdx.x >> 6;
    const int tile = blockIdx.x * 4 + wv;      // 0..8319
    const int n = lane & 15, q = lane >> 4;

    const int sg   = tile * 16 + n;
    const int b    = sg / NITEM;
    const int item = sg - b * NITEM;
    const float *Pr, *Qr;
    if (item == 0)       { Pr = P + h[b] * H1;                        Qr = Qt + b * H1; }
    else if (item <= 32) { Pr = P + h[b] * H1;                        Qr = Q + ns[b * 64 + item - 1] * H1; }
    else                 { Pr = P + ns[b * 64 + 32 + item - 33] * H1; Qr = Qt + b * H1; }

    floatx4 acc[4];
    #pragma unroll
    for (int nt = 0; nt < 4; ++nt) acc[nt] = (floatx4){0.f, 0.f, 0.f, 0.f};

    #pragma unroll
    for (int kt = 0; kt < 4; ++kt) {
        const int kb = kt * 32 + q * 8;
        float4 p0 = *(const float4*)(Pr + kb);
        float4 p1 = *(const float4*)(Pr + kb + 4);
        float4 q0 = *(const float4*)(Qr + kb);
        float4 q1 = *(const float4*)(Qr + kb + 4);
        union { short8 s; unsigned u[4]; } A;
        A.u[0] = pkbf(fmaxf(p0.x + q0.x, 0.f), fmaxf(p0.y + q0.y, 0.f));
        A.u[1] = pkbf(fmaxf(p0.z + q0.z, 0.f), fmaxf(p0.w + q0.w, 0.f));
        A.u[2] = pkbf(fmaxf(p1.x + q1.x, 0.f), fmaxf(p1.y + q1.y, 0.f));
        A.u[3] = pkbf(fmaxf(p1.z + q1.z, 0.f), fmaxf(p1.w + q1.w, 0.f));
        #pragma unroll
        for (int nt = 0; nt < 4; ++nt) {
            short8 bf = W2f[(kt * 4 + nt) * 64 + lane];
            acc[nt] = __builtin_amdgcn_mfma_f32_16x16x32_bf16(A.s, bf, acc[nt], 0, 0, 0);
        }
    }

    float part[4];
    #pragma unroll
    for (int reg = 0; reg < 4; ++reg) {
        float sum = 0.f;
        #pragma unroll
        for (int nt = 0; nt < 4; ++nt) {
            int j = nt * 16 + n;
            sum = fmaf(fmaxf(acc[nt][reg] + b2[j], 0.f), W3[j], sum);
        }
        part[reg] = sum;
    }
    #pragma unroll
    for (int m = 1; m < 16; m <<= 1) {
        #pragma unroll
        for (int reg = 0; reg < 4; ++reg)
            part[reg] += __shfl_xor(part[reg], m, 64);
    }
    if (n == 0) {
        const float base3 = b3[0];
        #pragma unroll
        for (int reg = 0; reg < 4; ++reg) {
            int gid = tile * 16 + q * 4 + reg;
            int bb  = gid / NITEM;
            int it  = gid - bb * NITEM;
            float val = part[reg] + base3;
            if (it == 0) out[bb] = val;
            else         out[BATCH + bb * 64 + (it - 1)] = val;
        }
    }
}

extern "C" void kernel_launch(void* const* d_in, const int* in_sizes, int n_in,
                              void* d_out, int out_size, void* d_ws, size_t ws_size,
                              hipStream_t stream) {
    const float* embed = (const float*)d_in[0];
    const float* W1    = (const float*)d_in[1];
    const float* b1    = (const float*)d_in[2];
    const float* W2    = (const float*)d_in[3];
    const float* b2    = (const float*)d_in[4];
    const float* W3    = (const float*)d_in[5];
    const float* b3    = (const float*)d_in[6];
    const int*   h     = (const int*)d_in[7];
    const int*   t     = (const int*)d_in[8];
    const int*   ns    = (const int*)d_in[9];
    float* out = (float*)d_out;
    float* ws  = (float*)d_ws;   // slab | W2f | W1f | X1 | X2  (~7.5 MB)

    prep<<<318, 256, 0, stream>>>(embed, W1, W2, t, ws);
    layer1_mfma<<<756, 256, 0, stream>>>(ws, b1);          // 3024 waves
    score_mfma<<<(BATCH * NITEM) / 64, 256, 0, stream>>>(ws, b2, W3, b3,
                                                         h, ns, out);
}

// Round 7
// 117.506 us; speedup vs baseline: 1.7658x; 1.0228x over previous
//
#include <hip/hip_runtime.h>

#define DIM    512
#define BATCH  2048
#define NDRUG  2000
#define H1     128
#define H2     64
#define NITEM  65        // 1 pos + 64 neg per sample
#define SLAB   774144    // floats: P 2000x128 | Q 2000x128 | Qt 2048x128
// ws float offsets
#define W2F_OFF  (SLAB)               // 16 KB  W2 bf16 B-fragments
#define W1F_OFF  (W2F_OFF + 4096)     // 256 KB W1 bf16 B-fragments
#define LP       65                   // layer1 LDS pitch in short8 units (+1 pad)

typedef __attribute__((ext_vector_type(8))) short short8;
typedef __attribute__((ext_vector_type(4))) float floatx4;

// f32 -> bf16 RNE (bit trick; inputs finite)
__device__ inline unsigned f2bf(float x) {
    union { float f; unsigned u; } v; v.f = x;
    unsigned r = v.u + 0x7fffu + ((v.u >> 16) & 1u);
    return r >> 16;
}
__device__ inline unsigned pkbf(float a, float b) {
    return f2bf(a) | (f2bf(b) << 16);
}
__device__ inline short8 cvt8(const float* __restrict__ src) {
    float4 a = *(const float4*)src, b = *(const float4*)(src + 4);
    union { short8 s; unsigned u[4]; } v;
    v.u[0] = pkbf(a.x, a.y); v.u[1] = pkbf(a.z, a.w);
    v.u[2] = pkbf(b.x, b.y); v.u[3] = pkbf(b.z, b.w);
    return v.s;
}

// ---------------------------------------------------------------------------
// Kernel 1: weight packing only. 65 blocks x 256.
//  blk [0,64): W1f B-fragments (16384 lane-items)
//  blk 64:     W2f B-fragments (1024 lane-items)
// B-frag layout (mfma_f32_16x16x32_bf16): lane L holds
//   B[k = kt*32 + (L>>4)*8 + j][n = nt*16 + (L&15)], j = 0..7.
// W1f frag index = (half*16 + kt)*8 + nt.
// ---------------------------------------------------------------------------
__global__ __launch_bounds__(256) void pack_w(
    const float* __restrict__ W1, const float* __restrict__ W2,
    float* __restrict__ ws)
{
    const int blk = blockIdx.x, tid = threadIdx.x;
    if (blk < 64) {
        short8* W1f = (short8*)(ws + W1F_OFF);
        int item = blk * 256 + tid;                // < 16384
        int frag = item >> 6, lane = item & 63;
        int half = frag >> 7, kt = (frag >> 3) & 15, nt = frag & 7;
        int n = lane & 15, q = lane >> 4;
        short8 v;
        #pragma unroll
        for (int j = 0; j < 8; ++j) {
            int k = half * DIM + kt * 32 + q * 8 + j;
            v[j] = (short)f2bf(W1[k * H1 + nt * 16 + n]);
        }
        W1f[item] = v;
    } else {
        short8* W2f = (short8*)(ws + W2F_OFF);
        #pragma unroll
        for (int i = 0; i < 4; ++i) {
            int item = i * 256 + tid;              // < 1024
            int frag = item >> 6, lane = item & 63;
            int kt = frag >> 2, nt = frag & 3;
            int n = lane & 15, q = lane >> 4;
            short8 v;
            #pragma unroll
            for (int j = 0; j < 8; ++j)
                v[j] = (short)f2bf(W2[(kt * 32 + q * 8 + j) * H2 + nt * 16 + n]);
            W2f[item] = v;
        }
    }
}

// ---------------------------------------------------------------------------
// Kernel 2: layer-1 via MFMA, embed staged f32->bf16 straight into LDS in
// A-fragment order (no global X tables). 253 blocks x 256 (4 waves).
//  blk [0,125):   16 drug rows; 16 col-tiles (P nt0-7, Q nt0-7); 4 tiles/wave.
//  blk [125,253): 16 t-gathered rows; 8 col-tiles (Qt); 2 tiles/wave.
// LDS pitch 65 short8 -> 2-way max bank aliasing on ds_read_b128 (free).
// b1 folded into tail tables (Q, Qt); P stays bias-free (score adds Qtail).
// ---------------------------------------------------------------------------
__global__ __launch_bounds__(256) void layer1(
    const float* __restrict__ embed, const float* __restrict__ b1,
    const int* __restrict__ t, float* __restrict__ ws)
{
    __shared__ short8 ldsA[16 * LP];              // 16.6 KB
    const short8* W1f = (const short8*)(ws + W1F_OFF);
    const int blk = blockIdx.x, tid = threadIdx.x;
    const bool isPQ = blk < 125;
    const int rowbase = isPQ ? blk * 16 : (blk - 125) * 16;

    // Stage: 16 rows x 64 k-chunks (short8). 1024 units / 256 threads.
    #pragma unroll
    for (int i = 0; i < 4; ++i) {
        int u = i * 256 + tid;
        int r = u >> 6, c = u & 63;
        size_t grow = isPQ ? (size_t)(rowbase + r) : (size_t)t[rowbase + r];
        ldsA[r * LP + c] = cvt8(embed + grow * DIM + c * 8);
    }
    __syncthreads();

    const int lane = tid & 63, wv = tid >> 6;
    const int n = lane & 15, q = lane >> 4;

    if (isPQ) {
        const int T0 = wv * 4;                    // tiles T0..T0+3, same half
        const int half = (T0 >= 8) ? 1 : 0;       // 0 -> P, 1 -> Q
        floatx4 acc[4];
        #pragma unroll
        for (int i = 0; i < 4; ++i) acc[i] = (floatx4){0.f, 0.f, 0.f, 0.f};
        #pragma unroll
        for (int kt = 0; kt < 16; ++kt) {
            short8 a = ldsA[n * LP + kt * 4 + q];
            #pragma unroll
            for (int i = 0; i < 4; ++i) {
                int nt = (T0 + i) & 7;
                short8 bf = W1f[(size_t)(((half * 16 + kt) * 8) + nt) * 64 + lane];
                acc[i] = __builtin_amdgcn_mfma_f32_16x16x32_bf16(a, bf, acc[i], 0, 0, 0);
            }
        }
        float* tbl = ws + (half ? NDRUG * H1 : 0);
        #pragma unroll
        for (int i = 0; i < 4; ++i) {
            int nt = (T0 + i) & 7;
            float badd = half ? b1[nt * 16 + n] : 0.f;
            #pragma unroll
            for (int reg = 0; reg < 4; ++reg)
                tbl[(size_t)(rowbase + q * 4 + reg) * H1 + nt * 16 + n] =
                    acc[i][reg] + badd;
        }
    } else {
        const int T0 = wv * 2;                    // tiles T0, T0+1 (Qt, half 1)
        floatx4 acc[2];
        #pragma unroll
        for (int i = 0; i < 2; ++i) acc[i] = (floatx4){0.f, 0.f, 0.f, 0.f};
        #pragma unroll
        for (int kt = 0; kt < 16; ++kt) {
            short8 a = ldsA[n * LP + kt * 4 + q];
            #pragma unroll
            for (int i = 0; i < 2; ++i) {
                int nt = T0 + i;
                short8 bf = W1f[(size_t)(((16 + kt) * 8) + nt) * 64 + lane];
                acc[i] = __builtin_amdgcn_mfma_f32_16x16x32_bf16(a, bf, acc[i], 0, 0, 0);
            }
        }
        float* tbl = ws + 2 * (NDRUG * H1);
        #pragma unroll
        for (int i = 0; i < 2; ++i) {
            int nt = T0 + i;
            float badd = b1[nt * 16 + n];
            #pragma unroll
            for (int reg = 0; reg < 4; ++reg)
                tbl[(size_t)(rowbase + q * 4 + reg) * H1 + nt * 16 + n] =
                    acc[i][reg] + badd;
        }
    }
}

// ---------------------------------------------------------------------------
// Kernel 3: score via MFMA (unchanged from round 6, passed). One wave per
// 16 rows; layer-2 as 4kt x 4nt mfma_f32_16x16x32_bf16; A = relu(P + Qtail)
// built on the fly (b1 folded into Q/Qt); B = prepacked W2f. Epilogue
// relu+W3 in C-layout + 16-lane shuffle reduce.
// ---------------------------------------------------------------------------
__global__ __launch_bounds__(256) void score_mfma(
    const float* __restrict__ ws,
    const float* __restrict__ b2, const float* __restrict__ W3,
    const float* __restrict__ b3,
    const int* __restrict__ h, const int* __restrict__ ns,
    float* __restrict__ out)
{
    const float* P  = ws;
    const float* Q  = ws + NDRUG * H1;
    const float* Qt = Q + NDRUG * H1;
    const short8* W2f = (const short8*)(ws + W2F_OFF);

    const int lane = threadIdx.x & 63;
    const int wv   = threadIdx.x >> 6;
    const int tile = blockIdx.x * 4 + wv;      // 0..8319
    const int n = lane & 15, q = lane >> 4;

    const int sg   = tile * 16 + n;
    const int b    = sg / NITEM;
    const int item = sg - b * NITEM;
    const float *Pr, *Qr;
    if (item == 0)       { Pr = P + h[b] * H1;                        Qr = Qt + b * H1; }
    else if (item <= 32) { Pr = P + h[b] * H1;                        Qr = Q + ns[b * 64 + item - 1] * H1; }
    else                 { Pr = P + ns[b * 64 + 32 + item - 33] * H1; Qr = Qt + b * H1; }

    floatx4 acc[4];
    #pragma unroll
    for (int nt = 0; nt < 4; ++nt) acc[nt] = (floatx4){0.f, 0.f, 0.f, 0.f};

    #pragma unroll
    for (int kt = 0; kt < 4; ++kt) {
        const int kb = kt * 32 + q * 8;
        float4 p0 = *(const float4*)(Pr + kb);
        float4 p1 = *(const float4*)(Pr + kb + 4);
        float4 q0 = *(const float4*)(Qr + kb);
        float4 q1 = *(const float4*)(Qr + kb + 4);
        union { short8 s; unsigned u[4]; } A;
        A.u[0] = pkbf(fmaxf(p0.x + q0.x, 0.f), fmaxf(p0.y + q0.y, 0.f));
        A.u[1] = pkbf(fmaxf(p0.z + q0.z, 0.f), fmaxf(p0.w + q0.w, 0.f));
        A.u[2] = pkbf(fmaxf(p1.x + q1.x, 0.f), fmaxf(p1.y + q1.y, 0.f));
        A.u[3] = pkbf(fmaxf(p1.z + q1.z, 0.f), fmaxf(p1.w + q1.w, 0.f));
        #pragma unroll
        for (int nt = 0; nt < 4; ++nt) {
            short8 bf = W2f[(kt * 4 + nt) * 64 + lane];
            acc[nt] = __builtin_amdgcn_mfma_f32_16x16x32_bf16(A.s, bf, acc[nt], 0, 0, 0);
        }
    }

    float part[4];
    #pragma unroll
    for (int reg = 0; reg < 4; ++reg) {
        float sum = 0.f;
        #pragma unroll
        for (int nt = 0; nt < 4; ++nt) {
            int j = nt * 16 + n;
            sum = fmaf(fmaxf(acc[nt][reg] + b2[j], 0.f), W3[j], sum);
        }
        part[reg] = sum;
    }
    #pragma unroll
    for (int m = 1; m < 16; m <<= 1) {
        #pragma unroll
        for (int reg = 0; reg < 4; ++reg)
            part[reg] += __shfl_xor(part[reg], m, 64);
    }
    if (n == 0) {
        const float base3 = b3[0];
        #pragma unroll
        for (int reg = 0; reg < 4; ++reg) {
            int gid = tile * 16 + q * 4 + reg;
            int bb  = gid / NITEM;
            int it  = gid - bb * NITEM;
            float val = part[reg] + base3;
            if (it == 0) out[bb] = val;
            else         out[BATCH + bb * 64 + (it - 1)] = val;
        }
    }
}

extern "C" void kernel_launch(void* const* d_in, const int* in_sizes, int n_in,
                              void* d_out, int out_size, void* d_ws, size_t ws_size,
                              hipStream_t stream) {
    const float* embed = (const float*)d_in[0];
    const float* W1    = (const float*)d_in[1];
    const float* b1    = (const float*)d_in[2];
    const float* W2    = (const float*)d_in[3];
    const float* b2    = (const float*)d_in[4];
    const float* W3    = (const float*)d_in[5];
    const float* b3    = (const float*)d_in[6];
    const int*   h     = (const int*)d_in[7];
    const int*   t     = (const int*)d_in[8];
    const int*   ns    = (const int*)d_in[9];
    float* out = (float*)d_out;
    float* ws  = (float*)d_ws;   // slab | W2f | W1f  (~3.4 MB)

    pack_w<<<65, 256, 0, stream>>>(W1, W2, ws);
    layer1<<<253, 256, 0, stream>>>(embed, b1, t, ws);
    score_mfma<<<(BATCH * NITEM) / 64, 256, 0, stream>>>(ws, b2, W3, b3,
                                                         h, ns, out);
}